// Round 17
// baseline (169.313 us; speedup 1.0000x reference)
//
#include <hip/hip_runtime.h>
#include <hip/hip_bf16.h>
#include <stdint.h>

#define N_HEAD 16
#define HDIM 64
#define C_IN 256
#define D_MODEL 1024          // N_HEAD*HDIM
#define N_SP 64
#define L_SP 256
#define A_L 2
#define MS (N_SP * L_SP)      // 16384 spatial points
#define MA (N_SP * A_L * L_SP)// 32768 aux points
#define MT (MS + MA)
#define ATT_SCALE 0.125f

typedef __attribute__((ext_vector_type(8))) short bf16x8;
typedef __attribute__((ext_vector_type(4))) float f32x4;
typedef __attribute__((ext_vector_type(8))) unsigned short u16x8;
typedef __attribute__((ext_vector_type(4))) unsigned int u32x4;

static __device__ __forceinline__ __hip_bfloat16 f2bf(float v) { return __float2bfloat16(v); }
static __device__ __forceinline__ unsigned short bfbits(float v) {
    union { __hip_bfloat16 h; unsigned short u; } cv;
    cv.h = __float2bfloat16(v);
    return cv.u;
}
static __device__ __forceinline__ float s2f(short u) {
    union { unsigned int i; float f; } c;
    c.i = ((unsigned int)(unsigned short)u) << 16;
    return c.f;
}

// ---------------- weight prep: fp32 -> bf16, natural q|k|v order ----------------
__global__ __launch_bounds__(256) void prep_weights(
    const float* __restrict__ wq, const float* __restrict__ bq,
    const float* __restrict__ wk, const float* __restrict__ bk,
    const float* __restrict__ wv, const float* __restrict__ bv,
    const float* __restrict__ wo,
    __hip_bfloat16* __restrict__ Wqkv, float* __restrict__ BiasQKV,
    __hip_bfloat16* __restrict__ WoB)
{
    int idx = blockIdx.x * 256 + threadIdx.x;   // grid covers 3*1024*256
    int row = idx >> 8, col = idx & 255;
    const float* w = (row < D_MODEL) ? wq : (row < 2 * D_MODEL) ? wk : wv;
    Wqkv[idx] = f2bf(w[(size_t)(row & (D_MODEL - 1)) * C_IN + col]);
    if (col == 0) {
        const float* b = (row < D_MODEL) ? bq : (row < 2 * D_MODEL) ? bk : bv;
        BiasQKV[row] = b[row & (D_MODEL - 1)];
    }
    if (idx < C_IN * D_MODEL) WoB[idx] = f2bf(wo[idx]);
}

// ---------------- input transpose: x [256,MS] & ax [256,MA] fp32 -> XtAll [MT,256] bf16 ----------------
__global__ __launch_bounds__(256) void transpose_in(
    const float* __restrict__ x, const float* __restrict__ ax,
    __hip_bfloat16* __restrict__ XtAll)
{
    __shared__ float tile[32][33];
    const int tx = threadIdx.x, ty = threadIdx.y;
    const int bx = blockIdx.x;
    const float* src; int M, m0, drow0;
    if (bx < MS / 32) { src = x;  M = MS; m0 = bx * 32;              drow0 = m0; }
    else              { src = ax; M = MA; m0 = (bx - MS / 32) * 32;  drow0 = MS + m0; }
    const int c0 = blockIdx.y * 32;
#pragma unroll
    for (int j = 0; j < 32; j += 8)
        tile[ty + j][tx] = src[(size_t)(c0 + ty + j) * M + m0 + tx];
    __syncthreads();
#pragma unroll
    for (int j = 0; j < 32; j += 8)
        XtAll[(size_t)(drow0 + ty + j) * C_IN + c0 + tx] = f2bf(tile[tx][ty + j]);
}

// ---------------- qkv proj: C[MS,3072] = Xt * Wqkv^T + bias[col] ----------------
// 128x128 tile, BK=64, 4 waves, reg-staged, XCD swizzle, T2 XOR LDS swizzle,
// coalesced repack epilogue. Ctile uses row-keyed chunk-XOR (no padding) so
// total LDS = 32768 B exactly.
__global__ __launch_bounds__(256) void gemm_proj(
    const __hip_bfloat16* __restrict__ A,
    const __hip_bfloat16* __restrict__ B,
    __hip_bfloat16* __restrict__ C,
    const float* __restrict__ bias,
    int M, int N, int K)
{
    __shared__ __align__(16) char lds[32768];
    __hip_bfloat16* As = (__hip_bfloat16*)lds;
    __hip_bfloat16* Bs = As + 128 * 64;
    __hip_bfloat16* Ct = (__hip_bfloat16*)lds;          // [128][128], chunk-XOR swizzled

    const int tid = threadIdx.x;
    const int lane = tid & 63;
    const int w = tid >> 6;
    const int wr = w >> 1, wc = w & 1;
    const int fr = lane & 15, fq = lane >> 4;

    const int nwg = gridDim.x * gridDim.y;
    const int lin = blockIdx.y * gridDim.x + blockIdx.x;
    const int qq = nwg >> 3, rr = nwg & 7;
    const int xcd = lin & 7, ix = lin >> 3;
    const int nlin = (xcd < rr) ? xcd * (qq + 1) + ix
                                : rr * (qq + 1) + (xcd - rr) * qq + ix;
    const int bx = nlin % gridDim.x, by = nlin / gridDim.x;

    const int i0 = by * 128, j0 = bx * 128;
    const int srow = tid >> 3, sch = (tid & 7) << 3;
    const int scolsw = sch ^ ((srow & 7) << 3);        // write-side swizzle
    const int rdsw = (fr & 7) << 3;                    // read-side swizzle

    f32x4 acc[4][4];
#pragma unroll
    for (int a = 0; a < 4; ++a)
#pragma unroll
        for (int b = 0; b < 4; ++b) acc[a][b] = (f32x4){0.f, 0.f, 0.f, 0.f};

    for (int k0 = 0; k0 < K; k0 += 64) {
        u32x4 ra[4], rb[4];
#pragma unroll
        for (int is = 0; is < 4; ++is) {
            int row = is * 32 + srow;
            ra[is] = *(const u32x4*)(A + (size_t)(i0 + row) * K + k0 + sch);
            rb[is] = *(const u32x4*)(B + (size_t)(j0 + row) * K + k0 + sch);
        }
#pragma unroll
        for (int is = 0; is < 4; ++is) {
            int row = is * 32 + srow;
            *(u32x4*)(As + row * 64 + scolsw) = ra[is];
            *(u32x4*)(Bs + row * 64 + scolsw) = rb[is];
        }
        __syncthreads();
#pragma unroll
        for (int kk = 0; kk < 64; kk += 32) {
            bf16x8 af[4], bb[4];
#pragma unroll
            for (int mi = 0; mi < 4; ++mi)
                af[mi] = *(const bf16x8*)(As + (wr * 64 + mi * 16 + fr) * 64 + ((kk + fq * 8) ^ rdsw));
#pragma unroll
            for (int ni = 0; ni < 4; ++ni)
                bb[ni] = *(const bf16x8*)(Bs + (wc * 64 + ni * 16 + fr) * 64 + ((kk + fq * 8) ^ rdsw));
#pragma unroll
            for (int mi = 0; mi < 4; ++mi)
#pragma unroll
                for (int ni = 0; ni < 4; ++ni)
                    acc[mi][ni] = __builtin_amdgcn_mfma_f32_16x16x32_bf16(
                        af[mi], bb[ni], acc[mi][ni], 0, 0, 0);
        }
        __syncthreads();
    }

    // epilogue: acc -> Ctile (bias, chunk-XOR) -> coalesced 256B row-segment stores
    float bcol[4];
#pragma unroll
    for (int ni = 0; ni < 4; ++ni) bcol[ni] = bias[j0 + wc * 64 + ni * 16 + fr];
#pragma unroll
    for (int mi = 0; mi < 4; ++mi)
#pragma unroll
        for (int r = 0; r < 4; ++r) {
            int row = wr * 64 + mi * 16 + fq * 4 + r;
            int key = (row & 7) << 3;
#pragma unroll
            for (int ni = 0; ni < 4; ++ni)
                Ct[row * 128 + ((wc * 64 + ni * 16 + fr) ^ key)] = f2bf(acc[mi][ni][r] + bcol[ni]);
        }
    __syncthreads();

    const int rr2 = tid >> 4, cc = tid & 15;
#pragma unroll
    for (int pass = 0; pass < 8; ++pass) {
        int row = pass * 16 + rr2;
        *(u16x8*)(C + (size_t)(i0 + row) * N + j0 + (cc << 3)) =
            *(const u16x8*)(Ct + row * 128 + ((cc ^ (row & 7)) << 3));
    }
}

// ---------------- fused aux-KV projection + windowed attention ----------------
// Block = (n, head h, 64-l tile). Phase A: aux tile [128 rows(a,ll) x 128 ch(k|v)]
//   = Xaux x W_h^T + bias -> LDS (T2-swizzled staging; round-13 direct-load was 2x slower).
// aux stored with row-keyed chunk-XOR (no padding): LDS = 32768 exactly.
// Phase B fully AFTER phase A (round-11 ordering): minimizes live VGPR during phase A
//   so ~5 waves/SIMD fit naturally (round-16: early-issue pushed VGPR to 116 -> capped
//   at 4; round-15: forcing via __launch_bounds__(,5) caused catastrophic spill).
// Window w at position n reads source row nn = ((3n+w)&63) + ((3n+w)>>6) - 1 (zero-padded).
__global__ __launch_bounds__(256) void attn_fused(
    const __hip_bfloat16* __restrict__ XtAll,
    const __hip_bfloat16* __restrict__ Wqkv,
    const float* __restrict__ BiasQKV,
    __hip_bfloat16* qkv)                      // [MS, 3072]; q-cols become ATT
{
    __shared__ __align__(16) char ldsraw[32768];
    __hip_bfloat16* As  = (__hip_bfloat16*)ldsraw;            // [128][64]
    __hip_bfloat16* Bs  = (__hip_bfloat16*)(ldsraw + 16384);  // [128][64]
    __hip_bfloat16* aux = (__hip_bfloat16*)ldsraw;            // [128][128] chunk-XOR

    // n-grouped XCD swizzle: xcd = flat&7 owns n in [xcd*8, xcd*8+8)
    const int flat = blockIdx.x;
    const int xcd = flat & 7, idx = flat >> 3;
    const int n  = xcd * 8 + (idx & 7);
    const int h  = (idx >> 3) & 15;
    const int lt = idx >> 7;

    const int tid = threadIdx.x;
    const int lane = tid & 63;
    const int w = tid >> 6;
    const int wr = w >> 1, wc = w & 1;
    const int fr = lane & 15, fq = lane >> 4;
    const int srow = tid >> 3, sch = (tid & 7) << 3;
    const int scolsw = sch ^ ((srow & 7) << 3);
    const int rdsw = (fr & 7) << 3;

    // ---------- phase A: aux k|v tile via MFMA ----------
    f32x4 acc[4][4];
#pragma unroll
    for (int a = 0; a < 4; ++a)
#pragma unroll
        for (int b = 0; b < 4; ++b) acc[a][b] = (f32x4){0.f, 0.f, 0.f, 0.f};

    for (int k0 = 0; k0 < 256; k0 += 64) {
        u32x4 ra[4], rb[4];
#pragma unroll
        for (int is = 0; is < 4; ++is) {
            int r = is * 32 + srow;
            int arow = MS + n * 512 + (r >> 6) * 256 + lt * 64 + (r & 63);
            int brow = 1024 + (r >> 6) * 1024 + h * 64 + (r & 63);
            ra[is] = *(const u32x4*)(XtAll + (size_t)arow * 256 + k0 + sch);
            rb[is] = *(const u32x4*)(Wqkv + (size_t)brow * 256 + k0 + sch);
        }
#pragma unroll
        for (int is = 0; is < 4; ++is) {
            int r = is * 32 + srow;
            *(u32x4*)(As + r * 64 + scolsw) = ra[is];
            *(u32x4*)(Bs + r * 64 + scolsw) = rb[is];
        }
        __syncthreads();
#pragma unroll
        for (int kk = 0; kk < 64; kk += 32) {
            bf16x8 af[4], bb[4];
#pragma unroll
            for (int mi = 0; mi < 4; ++mi)
                af[mi] = *(const bf16x8*)(As + (wr * 64 + mi * 16 + fr) * 64 + ((kk + fq * 8) ^ rdsw));
#pragma unroll
            for (int ni = 0; ni < 4; ++ni)
                bb[ni] = *(const bf16x8*)(Bs + (wc * 64 + ni * 16 + fr) * 64 + ((kk + fq * 8) ^ rdsw));
#pragma unroll
            for (int mi = 0; mi < 4; ++mi)
#pragma unroll
                for (int ni = 0; ni < 4; ++ni)
                    acc[mi][ni] = __builtin_amdgcn_mfma_f32_16x16x32_bf16(
                        af[mi], bb[ni], acc[mi][ni], 0, 0, 0);
        }
        __syncthreads();   // also fences As/Bs before aux overwrite
    }

    float bcol[4];
#pragma unroll
    for (int ni = 0; ni < 4; ++ni)
        bcol[ni] = BiasQKV[1024 + wc * 1024 + h * 64 + ni * 16 + fr];

#pragma unroll
    for (int mi = 0; mi < 4; ++mi)
#pragma unroll
        for (int r = 0; r < 4; ++r) {
            int row = wr * 64 + mi * 16 + fq * 4 + r;
            int key = (row & 7) << 3;
#pragma unroll
            for (int ni = 0; ni < 4; ++ni) {
                int col = wc * 64 + ni * 16 + fr;
                aux[row * 128 + (col ^ key)] = f2bf(acc[mi][ni][r] + bcol[ni]);
            }
        }
    __syncthreads();

    // ---------- phase B: attention, 64 points x 4 subs (16 ch each) ----------
    const int sub = tid & 3;
    const int ll = tid >> 2;
    const int l = lt * 64 + ll;
    const int m = n * L_SP + l;
    const int ch = sub * 16;

    int src[3]; float val[3];
#pragma unroll
    for (int wd = 0; wd < 3; ++wd) {
        int f = n * 3 + wd;
        int un = f >> 6;
        int nn = (f & 63) + un - 1;
        bool ok = (nn >= 0) && (nn < N_SP);
        src[wd] = ok ? nn : 0;
        val[wd] = ok ? 1.f : 0.f;
    }

    // all loads issued up front (deep MLP within phase B)
    __hip_bfloat16* qp = qkv + (size_t)m * 3072 + h * 64 + ch;
    bf16x8 q0 = *(const bf16x8*)qp, q1 = *(const bf16x8*)(qp + 8);
    bf16x8 kg[3][2], vg[3][2];
#pragma unroll
    for (int wd = 0; wd < 3; ++wd) {
        const __hip_bfloat16* rowp = qkv + (size_t)(src[wd] * L_SP + l) * 3072 + h * 64 + ch;
        kg[wd][0] = *(const bf16x8*)(rowp + 1024);
        kg[wd][1] = *(const bf16x8*)(rowp + 1024 + 8);
        vg[wd][0] = *(const bf16x8*)(rowp + 2048);
        vg[wd][1] = *(const bf16x8*)(rowp + 2048 + 8);
    }
    bf16x8 ka[2][2], va[2][2];
#pragma unroll
    for (int a = 0; a < 2; ++a) {
        const int row = a * 64 + ll;
        const int k8 = row & 7;
        const __hip_bfloat16* base = aux + row * 128;
        ka[a][0] = *(const bf16x8*)(base + (((sub * 2)     ^ k8) << 3));
        ka[a][1] = *(const bf16x8*)(base + (((sub * 2 + 1) ^ k8) << 3));
        va[a][0] = *(const bf16x8*)(base + (((8 + sub * 2) ^ k8) << 3));
        va[a][1] = *(const bf16x8*)(base + (((9 + sub * 2) ^ k8) << 3));
    }

    float s[5];
#pragma unroll
    for (int i = 0; i < 3; ++i) {
        float d = 0.f;
#pragma unroll
        for (int j = 0; j < 8; ++j)
            d += s2f(q0[j]) * s2f(kg[i][0][j]) + s2f(q1[j]) * s2f(kg[i][1][j]);
        s[i] = d;
    }
#pragma unroll
    for (int a = 0; a < 2; ++a) {
        float d = 0.f;
#pragma unroll
        for (int j = 0; j < 8; ++j)
            d += s2f(q0[j]) * s2f(ka[a][0][j]) + s2f(q1[j]) * s2f(ka[a][1][j]);
        s[3 + a] = d;
    }
#pragma unroll
    for (int i = 0; i < 5; ++i) {
        s[i] += __shfl_xor(s[i], 1);
        s[i] += __shfl_xor(s[i], 2);
        s[i] *= ATT_SCALE;
    }
    s[0] *= val[0]; s[1] *= val[1]; s[2] *= val[2];   // padded window -> score exactly 0

    float mx = fmaxf(fmaxf(fmaxf(s[0], s[1]), fmaxf(s[2], s[3])), s[4]);
    float e0 = __expf(s[0] - mx), e1 = __expf(s[1] - mx), e2 = __expf(s[2] - mx);
    float e3 = __expf(s[3] - mx), e4 = __expf(s[4] - mx);
    float inv = 1.f / (e0 + e1 + e2 + e3 + e4);
    float al[5];
    al[0] = e0 * inv * val[0];   // padded window: v==0 -> zero contribution
    al[1] = e1 * inv * val[1];
    al[2] = e2 * inv * val[2];
    al[3] = e3 * inv;
    al[4] = e4 * inv;

#pragma unroll
    for (int g = 0; g < 2; ++g) {
        u16x8 pack;
#pragma unroll
        for (int j = 0; j < 8; ++j) {
            float o = al[0] * s2f(vg[0][g][j]) + al[1] * s2f(vg[1][g][j])
                    + al[2] * s2f(vg[2][g][j]) + al[3] * s2f(va[0][g][j])
                    + al[4] * s2f(va[1][g][j]);
            pack[j] = bfbits(o);
        }
        *(u16x8*)(qp + g * 8) = pack;     // overwrite own q-slice with ATT
    }
}

// ---------------- out = WoB[256,1024] * ATT(q-cols of qkv, ldb=3072)^T + bo ----------------
// fp32 out, coalesced repack epilogue; Ctf uses f32 chunk-XOR -> LDS = 32768 exactly.
__global__ __launch_bounds__(256) void gemm_out(
    const __hip_bfloat16* __restrict__ A,     // WoB, lda 1024
    const __hip_bfloat16* __restrict__ B,     // qkv, ldb 3072, cols 0..1023 = ATT
    float* __restrict__ C,                    // [256, MS]
    const float* __restrict__ bo)
{
    __shared__ __align__(16) char lds[32768];
    __hip_bfloat16* As = (__hip_bfloat16*)lds;
    __hip_bfloat16* Bs = As + 128 * 64;
    float* Ctf = (float*)lds;                           // [64][128] chunk-XOR

    const int tid = threadIdx.x;
    const int lane = tid & 63;
    const int w = tid >> 6;
    const int wr = w >> 1, wc = w & 1;
    const int fr = lane & 15, fq = lane >> 4;

    const int nwg = gridDim.x * gridDim.y;
    const int lin = blockIdx.y * gridDim.x + blockIdx.x;
    const int qq = nwg >> 3, rr = nwg & 7;
    const int xcd = lin & 7, ix = lin >> 3;
    const int nlin = (xcd < rr) ? xcd * (qq + 1) + ix
                                : rr * (qq + 1) + (xcd - rr) * qq + ix;
    const int bx = nlin % gridDim.x, by = nlin / gridDim.x;

    const int i0 = by * 128, j0 = bx * 128;
    const int srow = tid >> 3, sch = (tid & 7) << 3;
    const int scolsw = sch ^ ((srow & 7) << 3);
    const int rdsw = (fr & 7) << 3;

    f32x4 acc[4][4];
#pragma unroll
    for (int a = 0; a < 4; ++a)
#pragma unroll
        for (int b = 0; b < 4; ++b) acc[a][b] = (f32x4){0.f, 0.f, 0.f, 0.f};

    for (int k0 = 0; k0 < 1024; k0 += 64) {
        u32x4 ra[4], rb[4];
#pragma unroll
        for (int is = 0; is < 4; ++is) {
            int row = is * 32 + srow;
            ra[is] = *(const u32x4*)(A + (size_t)(i0 + row) * 1024 + k0 + sch);
            rb[is] = *(const u32x4*)(B + (size_t)(j0 + row) * 3072 + k0 + sch);
        }
#pragma unroll
        for (int is = 0; is < 4; ++is) {
            int row = is * 32 + srow;
            *(u32x4*)(As + row * 64 + scolsw) = ra[is];
            *(u32x4*)(Bs + row * 64 + scolsw) = rb[is];
        }
        __syncthreads();
#pragma unroll
        for (int kk = 0; kk < 64; kk += 32) {
            bf16x8 af[4], bb[4];
#pragma unroll
            for (int mi = 0; mi < 4; ++mi)
                af[mi] = *(const bf16x8*)(As + (wr * 64 + mi * 16 + fr) * 64 + ((kk + fq * 8) ^ rdsw));
#pragma unroll
            for (int ni = 0; ni < 4; ++ni)
                bb[ni] = *(const bf16x8*)(Bs + (wc * 64 + ni * 16 + fr) * 64 + ((kk + fq * 8) ^ rdsw));
#pragma unroll
            for (int mi = 0; mi < 4; ++mi)
#pragma unroll
                for (int ni = 0; ni < 4; ++ni)
                    acc[mi][ni] = __builtin_amdgcn_mfma_f32_16x16x32_bf16(
                        af[mi], bb[ni], acc[mi][ni], 0, 0, 0);
        }
        __syncthreads();
    }

    // epilogue: two 64-row passes -> LDS f32 tile (chunk-XOR) -> 128B f32x4 stores
#pragma unroll
    for (int half = 0; half < 2; ++half) {
        if (wr == half) {
#pragma unroll
            for (int mi = 0; mi < 4; ++mi)
#pragma unroll
                for (int r = 0; r < 4; ++r) {
                    int lrow = mi * 16 + fq * 4 + r;               // 0..63
                    int key = (lrow & 7) << 2;
                    float bv = bo[i0 + half * 64 + lrow];
#pragma unroll
                    for (int ni = 0; ni < 4; ++ni)
                        Ctf[lrow * 128 + ((wc * 64 + ni * 16 + fr) ^ key)] = acc[mi][ni][r] + bv;
                }
        }
        __syncthreads();
#pragma unroll
        for (int it = 0; it < 8; ++it) {
            int lrow = it * 8 + (tid >> 5);
            int g = tid & 31;
            *(f32x4*)(C + (size_t)(i0 + half * 64 + lrow) * MS + j0 + g * 4) =
                *(const f32x4*)(Ctf + lrow * 128 + ((g ^ (lrow & 7)) << 2));
        }
        __syncthreads();
    }
}

// ---------------- launch ----------------
extern "C" void kernel_launch(void* const* d_in, const int* in_sizes, int n_in,
                              void* d_out, int out_size, void* d_ws, size_t ws_size,
                              hipStream_t stream) {
    const float* x  = (const float*)d_in[0];
    const float* ax = (const float*)d_in[1];
    const float* wq = (const float*)d_in[2];
    const float* bq = (const float*)d_in[3];
    const float* wk = (const float*)d_in[4];
    const float* bk = (const float*)d_in[5];
    const float* wv = (const float*)d_in[6];
    const float* bv = (const float*)d_in[7];
    const float* wo = (const float*)d_in[8];
    const float* bo = (const float*)d_in[9];

    auto pad = [](size_t b) { return (b + 255) & ~(size_t)255; };
    char* p = (char*)d_ws;
    auto alloc = [&](size_t bytes) { char* r = p; p += pad(bytes); return r; };

    __hip_bfloat16* Wqkv    = (__hip_bfloat16*)alloc((size_t)3 * D_MODEL * C_IN * 2); // 1.5 MB
    float*          BiasQKV = (float*)alloc((size_t)3 * D_MODEL * 4);
    __hip_bfloat16* WoB     = (__hip_bfloat16*)alloc((size_t)C_IN * D_MODEL * 2);     // 0.5 MB
    __hip_bfloat16* XtAll   = (__hip_bfloat16*)alloc((size_t)MT * C_IN * 2);          // 25.2 MB
    __hip_bfloat16* qkv_c   = (__hip_bfloat16*)alloc((size_t)MS * 3 * D_MODEL * 2);   // 100.7 MB
    // total ~128 MB << ws_size

    prep_weights<<<dim3(3 * D_MODEL * C_IN / 256), 256, 0, stream>>>(
        wq, bq, wk, bk, wv, bv, wo, Wqkv, BiasQKV, WoB);

    transpose_in<<<dim3(MT / 32, C_IN / 32), dim3(32, 8), 0, stream>>>(x, ax, XtAll);

    // qkv_c[MS, 3072] = XtAll[0..MS) * Wqkv^T (+bias per col)
    gemm_proj<<<dim3(3 * D_MODEL / 128, MS / 128), 256, 0, stream>>>(
        XtAll, Wqkv, qkv_c, BiasQKV, MS, 3 * D_MODEL, C_IN);

    // fused aux-KV projection + attention; ATT lands in q-columns of qkv_c
    attn_fused<<<dim3(N_SP * N_HEAD * 4), 256, 0, stream>>>(
        XtAll, Wqkv, BiasQKV, qkv_c);

    // out[256, MS] = WoB * ATT^T + bo
    gemm_out<<<dim3(MS / 128, C_IN / 128), 256, 0, stream>>>(
        WoB, qkv_c, (float*)d_out, bo);
}

// Round 18
// 159.661 us; speedup vs baseline: 1.0605x; 1.0605x over previous
//
#include <hip/hip_runtime.h>
#include <hip/hip_bf16.h>
#include <stdint.h>

#define N_HEAD 16
#define HDIM 64
#define C_IN 256
#define D_MODEL 1024          // N_HEAD*HDIM
#define N_SP 64
#define L_SP 256
#define A_L 2
#define MS (N_SP * L_SP)      // 16384 spatial points
#define MA (N_SP * A_L * L_SP)// 32768 aux points
#define MT (MS + MA)
#define ATT_SCALE 0.125f
#define AUXP 136              // padded LDS row for aux k|v tile
#define CTP 136               // padded Ctile row (bf16 elems)

typedef __attribute__((ext_vector_type(8))) short bf16x8;
typedef __attribute__((ext_vector_type(4))) float f32x4;
typedef __attribute__((ext_vector_type(8))) unsigned short u16x8;
typedef __attribute__((ext_vector_type(4))) unsigned int u32x4;

static __device__ __forceinline__ __hip_bfloat16 f2bf(float v) { return __float2bfloat16(v); }
static __device__ __forceinline__ unsigned short bfbits(float v) {
    union { __hip_bfloat16 h; unsigned short u; } cv;
    cv.h = __float2bfloat16(v);
    return cv.u;
}
static __device__ __forceinline__ float s2f(short u) {
    union { unsigned int i; float f; } c;
    c.i = ((unsigned int)(unsigned short)u) << 16;
    return c.f;
}

// ---------------- weight prep: fp32 -> bf16, natural q|k|v order ----------------
__global__ __launch_bounds__(256) void prep_weights(
    const float* __restrict__ wq, const float* __restrict__ bq,
    const float* __restrict__ wk, const float* __restrict__ bk,
    const float* __restrict__ wv, const float* __restrict__ bv,
    const float* __restrict__ wo,
    __hip_bfloat16* __restrict__ Wqkv, float* __restrict__ BiasQKV,
    __hip_bfloat16* __restrict__ WoB)
{
    int idx = blockIdx.x * 256 + threadIdx.x;   // grid covers 3*1024*256
    int row = idx >> 8, col = idx & 255;
    const float* w = (row < D_MODEL) ? wq : (row < 2 * D_MODEL) ? wk : wv;
    Wqkv[idx] = f2bf(w[(size_t)(row & (D_MODEL - 1)) * C_IN + col]);
    if (col == 0) {
        const float* b = (row < D_MODEL) ? bq : (row < 2 * D_MODEL) ? bk : bv;
        BiasQKV[row] = b[row & (D_MODEL - 1)];
    }
    if (idx < C_IN * D_MODEL) WoB[idx] = f2bf(wo[idx]);
}

// ---------------- input transpose: x [256,MS] & ax [256,MA] fp32 -> XtAll [MT,256] bf16 ----------------
__global__ __launch_bounds__(256) void transpose_in(
    const float* __restrict__ x, const float* __restrict__ ax,
    __hip_bfloat16* __restrict__ XtAll)
{
    __shared__ float tile[32][33];
    const int tx = threadIdx.x, ty = threadIdx.y;
    const int bx = blockIdx.x;
    const float* src; int M, m0, drow0;
    if (bx < MS / 32) { src = x;  M = MS; m0 = bx * 32;              drow0 = m0; }
    else              { src = ax; M = MA; m0 = (bx - MS / 32) * 32;  drow0 = MS + m0; }
    const int c0 = blockIdx.y * 32;
#pragma unroll
    for (int j = 0; j < 32; j += 8)
        tile[ty + j][tx] = src[(size_t)(c0 + ty + j) * M + m0 + tx];
    __syncthreads();
#pragma unroll
    for (int j = 0; j < 32; j += 8)
        XtAll[(size_t)(drow0 + ty + j) * C_IN + c0 + tx] = f2bf(tile[tx][ty + j]);
}

// ---------------- qkv proj: C[MS,3072] = Xt * Wqkv^T + bias[col] ----------------
// 128x128 tile, BK=64, 4 waves, reg-staged, XCD swizzle, T2 XOR LDS swizzle,
// coalesced repack epilogue (Ctile in LDS -> 256B-contiguous u16x8 stores).
__global__ __launch_bounds__(256) void gemm_proj(
    const __hip_bfloat16* __restrict__ A,
    const __hip_bfloat16* __restrict__ B,
    __hip_bfloat16* __restrict__ C,
    const float* __restrict__ bias,
    int M, int N, int K)
{
    __shared__ __align__(16) char lds[128 * CTP * 2];   // >= 2*128*64*2 stage
    __hip_bfloat16* As = (__hip_bfloat16*)lds;
    __hip_bfloat16* Bs = As + 128 * 64;
    __hip_bfloat16* Ct = (__hip_bfloat16*)lds;

    const int tid = threadIdx.x;
    const int lane = tid & 63;
    const int w = tid >> 6;
    const int wr = w >> 1, wc = w & 1;
    const int fr = lane & 15, fq = lane >> 4;

    const int nwg = gridDim.x * gridDim.y;
    const int lin = blockIdx.y * gridDim.x + blockIdx.x;
    const int qq = nwg >> 3, rr = nwg & 7;
    const int xcd = lin & 7, ix = lin >> 3;
    const int nlin = (xcd < rr) ? xcd * (qq + 1) + ix
                                : rr * (qq + 1) + (xcd - rr) * qq + ix;
    const int bx = nlin % gridDim.x, by = nlin / gridDim.x;

    const int i0 = by * 128, j0 = bx * 128;
    const int srow = tid >> 3, sch = (tid & 7) << 3;
    const int scolsw = sch ^ ((srow & 7) << 3);        // write-side swizzle
    const int rdsw = (fr & 7) << 3;                    // read-side swizzle

    f32x4 acc[4][4];
#pragma unroll
    for (int a = 0; a < 4; ++a)
#pragma unroll
        for (int b = 0; b < 4; ++b) acc[a][b] = (f32x4){0.f, 0.f, 0.f, 0.f};

    for (int k0 = 0; k0 < K; k0 += 64) {
        u32x4 ra[4], rb[4];
#pragma unroll
        for (int is = 0; is < 4; ++is) {
            int row = is * 32 + srow;
            ra[is] = *(const u32x4*)(A + (size_t)(i0 + row) * K + k0 + sch);
            rb[is] = *(const u32x4*)(B + (size_t)(j0 + row) * K + k0 + sch);
        }
#pragma unroll
        for (int is = 0; is < 4; ++is) {
            int row = is * 32 + srow;
            *(u32x4*)(As + row * 64 + scolsw) = ra[is];
            *(u32x4*)(Bs + row * 64 + scolsw) = rb[is];
        }
        __syncthreads();
#pragma unroll
        for (int kk = 0; kk < 64; kk += 32) {
            bf16x8 af[4], bb[4];
#pragma unroll
            for (int mi = 0; mi < 4; ++mi)
                af[mi] = *(const bf16x8*)(As + (wr * 64 + mi * 16 + fr) * 64 + ((kk + fq * 8) ^ rdsw));
#pragma unroll
            for (int ni = 0; ni < 4; ++ni)
                bb[ni] = *(const bf16x8*)(Bs + (wc * 64 + ni * 16 + fr) * 64 + ((kk + fq * 8) ^ rdsw));
#pragma unroll
            for (int mi = 0; mi < 4; ++mi)
#pragma unroll
                for (int ni = 0; ni < 4; ++ni)
                    acc[mi][ni] = __builtin_amdgcn_mfma_f32_16x16x32_bf16(
                        af[mi], bb[ni], acc[mi][ni], 0, 0, 0);
        }
        __syncthreads();
    }

    // epilogue: acc -> Ctile (bias added) -> coalesced 256B row-segment stores
    float bcol[4];
#pragma unroll
    for (int ni = 0; ni < 4; ++ni) bcol[ni] = bias[j0 + wc * 64 + ni * 16 + fr];
#pragma unroll
    for (int mi = 0; mi < 4; ++mi)
#pragma unroll
        for (int r = 0; r < 4; ++r) {
            int row = wr * 64 + mi * 16 + fq * 4 + r;
#pragma unroll
            for (int ni = 0; ni < 4; ++ni)
                Ct[row * CTP + wc * 64 + ni * 16 + fr] = f2bf(acc[mi][ni][r] + bcol[ni]);
        }
    __syncthreads();

    const int rr2 = tid >> 4, cc2 = (tid & 15) << 3;
#pragma unroll
    for (int pass = 0; pass < 8; ++pass) {
        int row = pass * 16 + rr2;
        *(u16x8*)(C + (size_t)(i0 + row) * N + j0 + cc2) =
            *(const u16x8*)(Ct + row * CTP + cc2);
    }
}

// ---------------- fused aux-KV projection + windowed attention ----------------
// Best-measured config (round 12, 159.7us total / 78us this kernel):
//  - phase-B globals issued FIRST (T14; worth ~3us vs issuing after phase A)
//  - LDS-staged phase A with T2 XOR swizzle (direct-load variant was 2x slower)
//  - padded aux rows AUXP=136 (chunk-XOR alternative costs ~3us of VALU)
//  - no min-waves launch bound (forcing 5 waves/EU spilled catastrophically, r15)
// Window w at position n reads source row nn = ((3n+w)&63) + ((3n+w)>>6) - 1 (zero-padded).
__global__ __launch_bounds__(256) void attn_fused(
    const __hip_bfloat16* __restrict__ XtAll,
    const __hip_bfloat16* __restrict__ Wqkv,
    const float* __restrict__ BiasQKV,
    __hip_bfloat16* qkv)                      // [MS, 3072]; q-cols become ATT
{
    __shared__ __align__(16) char ldsraw[36864];
    __hip_bfloat16* As  = (__hip_bfloat16*)ldsraw;            // [128][64]
    __hip_bfloat16* Bs  = (__hip_bfloat16*)(ldsraw + 16384);  // [128][64]
    __hip_bfloat16* aux = (__hip_bfloat16*)ldsraw;            // [128][AUXP]

    // n-grouped XCD swizzle: xcd = flat&7 owns n in [xcd*8, xcd*8+8)
    const int flat = blockIdx.x;
    const int xcd = flat & 7, idx = flat >> 3;
    const int n  = xcd * 8 + (idx & 7);
    const int h  = (idx >> 3) & 15;
    const int lt = idx >> 7;

    const int tid = threadIdx.x;
    const int lane = tid & 63;
    const int w = tid >> 6;
    const int wr = w >> 1, wc = w & 1;
    const int fr = lane & 15, fq = lane >> 4;
    const int srow = tid >> 3, sch = (tid & 7) << 3;
    const int scolsw = sch ^ ((srow & 7) << 3);
    const int rdsw = (fr & 7) << 3;

    // ---------- early-issue phase-B globals (T14) ----------
    const int sub = tid & 3;
    const int ll = tid >> 2;
    const int l = lt * 64 + ll;
    const int m = n * L_SP + l;
    const int ch = sub * 16;

    int src[3]; float val[3];
#pragma unroll
    for (int wd = 0; wd < 3; ++wd) {
        int f = n * 3 + wd;
        int un = f >> 6;
        int nn = (f & 63) + un - 1;
        bool ok = (nn >= 0) && (nn < N_SP);
        src[wd] = ok ? nn : 0;
        val[wd] = ok ? 1.f : 0.f;
    }

    __hip_bfloat16* qp = qkv + (size_t)m * 3072 + h * 64 + ch;
    bf16x8 q0 = *(const bf16x8*)qp, q1 = *(const bf16x8*)(qp + 8);
    bf16x8 kg[3][2], vg[3][2];
#pragma unroll
    for (int wd = 0; wd < 3; ++wd) {
        const __hip_bfloat16* rowp = qkv + (size_t)(src[wd] * L_SP + l) * 3072 + h * 64 + ch;
        kg[wd][0] = *(const bf16x8*)(rowp + 1024);
        kg[wd][1] = *(const bf16x8*)(rowp + 1024 + 8);
        vg[wd][0] = *(const bf16x8*)(rowp + 2048);
        vg[wd][1] = *(const bf16x8*)(rowp + 2048 + 8);
    }

    // ---------- phase A: aux k|v tile via MFMA ----------
    f32x4 acc[4][4];
#pragma unroll
    for (int a = 0; a < 4; ++a)
#pragma unroll
        for (int b = 0; b < 4; ++b) acc[a][b] = (f32x4){0.f, 0.f, 0.f, 0.f};

    for (int k0 = 0; k0 < 256; k0 += 64) {
        u32x4 ra[4], rb[4];
#pragma unroll
        for (int is = 0; is < 4; ++is) {
            int r = is * 32 + srow;
            int arow = MS + n * 512 + (r >> 6) * 256 + lt * 64 + (r & 63);
            int brow = 1024 + (r >> 6) * 1024 + h * 64 + (r & 63);
            ra[is] = *(const u32x4*)(XtAll + (size_t)arow * 256 + k0 + sch);
            rb[is] = *(const u32x4*)(Wqkv + (size_t)brow * 256 + k0 + sch);
        }
#pragma unroll
        for (int is = 0; is < 4; ++is) {
            int r = is * 32 + srow;
            *(u32x4*)(As + r * 64 + scolsw) = ra[is];
            *(u32x4*)(Bs + r * 64 + scolsw) = rb[is];
        }
        __syncthreads();
#pragma unroll
        for (int kk = 0; kk < 64; kk += 32) {
            bf16x8 af[4], bb[4];
#pragma unroll
            for (int mi = 0; mi < 4; ++mi)
                af[mi] = *(const bf16x8*)(As + (wr * 64 + mi * 16 + fr) * 64 + ((kk + fq * 8) ^ rdsw));
#pragma unroll
            for (int ni = 0; ni < 4; ++ni)
                bb[ni] = *(const bf16x8*)(Bs + (wc * 64 + ni * 16 + fr) * 64 + ((kk + fq * 8) ^ rdsw));
#pragma unroll
            for (int mi = 0; mi < 4; ++mi)
#pragma unroll
                for (int ni = 0; ni < 4; ++ni)
                    acc[mi][ni] = __builtin_amdgcn_mfma_f32_16x16x32_bf16(
                        af[mi], bb[ni], acc[mi][ni], 0, 0, 0);
        }
        __syncthreads();   // also fences As/Bs before aux overwrite
    }

    float bcol[4];
#pragma unroll
    for (int ni = 0; ni < 4; ++ni)
        bcol[ni] = BiasQKV[1024 + wc * 1024 + h * 64 + ni * 16 + fr];

#pragma unroll
    for (int mi = 0; mi < 4; ++mi)
#pragma unroll
        for (int r = 0; r < 4; ++r) {
            int row = wr * 64 + mi * 16 + fq * 4 + r;
#pragma unroll
            for (int ni = 0; ni < 4; ++ni) {
                int col = wc * 64 + ni * 16 + fr;
                aux[row * AUXP + col] = f2bf(acc[mi][ni][r] + bcol[ni]);
            }
        }
    __syncthreads();

    // ---------- phase B: attention, 64 points x 4 subs (16 ch each) ----------
    bf16x8 ka[2][2], va[2][2];
#pragma unroll
    for (int a = 0; a < 2; ++a) {
        const __hip_bfloat16* base = aux + (a * 64 + ll) * AUXP;
        ka[a][0] = *(const bf16x8*)(base + ch);
        ka[a][1] = *(const bf16x8*)(base + ch + 8);
        va[a][0] = *(const bf16x8*)(base + 64 + ch);
        va[a][1] = *(const bf16x8*)(base + 64 + ch + 8);
    }

    float s[5];
#pragma unroll
    for (int i = 0; i < 3; ++i) {
        float d = 0.f;
#pragma unroll
        for (int j = 0; j < 8; ++j)
            d += s2f(q0[j]) * s2f(kg[i][0][j]) + s2f(q1[j]) * s2f(kg[i][1][j]);
        s[i] = d;
    }
#pragma unroll
    for (int a = 0; a < 2; ++a) {
        float d = 0.f;
#pragma unroll
        for (int j = 0; j < 8; ++j)
            d += s2f(q0[j]) * s2f(ka[a][0][j]) + s2f(q1[j]) * s2f(ka[a][1][j]);
        s[3 + a] = d;
    }
#pragma unroll
    for (int i = 0; i < 5; ++i) {
        s[i] += __shfl_xor(s[i], 1);
        s[i] += __shfl_xor(s[i], 2);
        s[i] *= ATT_SCALE;
    }
    s[0] *= val[0]; s[1] *= val[1]; s[2] *= val[2];   // padded window -> score exactly 0

    float mx = fmaxf(fmaxf(fmaxf(s[0], s[1]), fmaxf(s[2], s[3])), s[4]);
    float e0 = __expf(s[0] - mx), e1 = __expf(s[1] - mx), e2 = __expf(s[2] - mx);
    float e3 = __expf(s[3] - mx), e4 = __expf(s[4] - mx);
    float inv = 1.f / (e0 + e1 + e2 + e3 + e4);
    float al[5];
    al[0] = e0 * inv * val[0];   // padded window: v==0 -> zero contribution
    al[1] = e1 * inv * val[1];
    al[2] = e2 * inv * val[2];
    al[3] = e3 * inv;
    al[4] = e4 * inv;

#pragma unroll
    for (int g = 0; g < 2; ++g) {
        u16x8 pack;
#pragma unroll
        for (int j = 0; j < 8; ++j) {
            float o = al[0] * s2f(vg[0][g][j]) + al[1] * s2f(vg[1][g][j])
                    + al[2] * s2f(vg[2][g][j]) + al[3] * s2f(va[0][g][j])
                    + al[4] * s2f(va[1][g][j]);
            pack[j] = bfbits(o);
        }
        *(u16x8*)(qp + g * 8) = pack;     // overwrite own q-slice with ATT
    }
}

// ---------------- out = WoB[256,1024] * ATT(q-cols of qkv, ldb=3072)^T + bo ----------------
__global__ __launch_bounds__(256) void gemm_out(
    const __hip_bfloat16* __restrict__ A,     // WoB, lda 1024
    const __hip_bfloat16* __restrict__ B,     // qkv, ldb 3072, cols 0..1023 = ATT
    float* __restrict__ C,                    // [256, MS]
    const float* __restrict__ bo)
{
    __shared__ __align__(16) __hip_bfloat16 As[128 * 64];
    __shared__ __align__(16) __hip_bfloat16 Bs[128 * 64];

    const int tid = threadIdx.x;
    const int lane = tid & 63;
    const int w = tid >> 6;
    const int wr = w >> 1, wc = w & 1;
    const int fr = lane & 15, fq = lane >> 4;

    const int nwg = gridDim.x * gridDim.y;
    const int lin = blockIdx.y * gridDim.x + blockIdx.x;
    const int qq = nwg >> 3, rr = nwg & 7;
    const int xcd = lin & 7, ix = lin >> 3;
    const int nlin = (xcd < rr) ? xcd * (qq + 1) + ix
                                : rr * (qq + 1) + (xcd - rr) * qq + ix;
    const int bx = nlin % gridDim.x, by = nlin / gridDim.x;

    const int i0 = by * 128, j0 = bx * 128;
    const int srow = tid >> 3, sch = (tid & 7) << 3;
    const int scolsw = sch ^ ((srow & 7) << 3);
    const int rdsw = (fr & 7) << 3;

    f32x4 acc[4][4];
#pragma unroll
    for (int a = 0; a < 4; ++a)
#pragma unroll
        for (int b = 0; b < 4; ++b) acc[a][b] = (f32x4){0.f, 0.f, 0.f, 0.f};

    for (int k0 = 0; k0 < 1024; k0 += 64) {
        u32x4 ra[4], rb[4];
#pragma unroll
        for (int is = 0; is < 4; ++is) {
            int row = is * 32 + srow;
            ra[is] = *(const u32x4*)(A + (size_t)(i0 + row) * 1024 + k0 + sch);
            rb[is] = *(const u32x4*)(B + (size_t)(j0 + row) * 3072 + k0 + sch);
        }
#pragma unroll
        for (int is = 0; is < 4; ++is) {
            int row = is * 32 + srow;
            *(u32x4*)(As + row * 64 + scolsw) = ra[is];
            *(u32x4*)(Bs + row * 64 + scolsw) = rb[is];
        }
        __syncthreads();
#pragma unroll
        for (int kk = 0; kk < 64; kk += 32) {
            bf16x8 af[4], bb[4];
#pragma unroll
            for (int mi = 0; mi < 4; ++mi)
                af[mi] = *(const bf16x8*)(As + (wr * 64 + mi * 16 + fr) * 64 + ((kk + fq * 8) ^ rdsw));
#pragma unroll
            for (int ni = 0; ni < 4; ++ni)
                bb[ni] = *(const bf16x8*)(Bs + (wc * 64 + ni * 16 + fr) * 64 + ((kk + fq * 8) ^ rdsw));
#pragma unroll
            for (int mi = 0; mi < 4; ++mi)
#pragma unroll
                for (int ni = 0; ni < 4; ++ni)
                    acc[mi][ni] = __builtin_amdgcn_mfma_f32_16x16x32_bf16(
                        af[mi], bb[ni], acc[mi][ni], 0, 0, 0);
        }
        __syncthreads();
    }

#pragma unroll
    for (int mi = 0; mi < 4; ++mi)
#pragma unroll
        for (int r = 0; r < 4; ++r) {
            int row = i0 + wr * 64 + mi * 16 + fq * 4 + r;
            float bv = bo[row];
#pragma unroll
            for (int ni = 0; ni < 4; ++ni) {
                int col = j0 + wc * 64 + ni * 16 + fr;
                C[(size_t)row * MS + col] = acc[mi][ni][r] + bv;
            }
        }
}

// ---------------- launch ----------------
extern "C" void kernel_launch(void* const* d_in, const int* in_sizes, int n_in,
                              void* d_out, int out_size, void* d_ws, size_t ws_size,
                              hipStream_t stream) {
    const float* x  = (const float*)d_in[0];
    const float* ax = (const float*)d_in[1];
    const float* wq = (const float*)d_in[2];
    const float* bq = (const float*)d_in[3];
    const float* wk = (const float*)d_in[4];
    const float* bk = (const float*)d_in[5];
    const float* wv = (const float*)d_in[6];
    const float* bv = (const float*)d_in[7];
    const float* wo = (const float*)d_in[8];
    const float* bo = (const float*)d_in[9];

    auto pad = [](size_t b) { return (b + 255) & ~(size_t)255; };
    char* p = (char*)d_ws;
    auto alloc = [&](size_t bytes) { char* r = p; p += pad(bytes); return r; };

    __hip_bfloat16* Wqkv    = (__hip_bfloat16*)alloc((size_t)3 * D_MODEL * C_IN * 2); // 1.5 MB
    float*          BiasQKV = (float*)alloc((size_t)3 * D_MODEL * 4);
    __hip_bfloat16* WoB     = (__hip_bfloat16*)alloc((size_t)C_IN * D_MODEL * 2);     // 0.5 MB
    __hip_bfloat16* XtAll   = (__hip_bfloat16*)alloc((size_t)MT * C_IN * 2);          // 25.2 MB
    __hip_bfloat16* qkv_c   = (__hip_bfloat16*)alloc((size_t)MS * 3 * D_MODEL * 2);   // 100.7 MB
    // total ~128 MB << ws_size

    prep_weights<<<dim3(3 * D_MODEL * C_IN / 256), 256, 0, stream>>>(
        wq, bq, wk, bk, wv, bv, wo, Wqkv, BiasQKV, WoB);

    transpose_in<<<dim3(MT / 32, C_IN / 32), dim3(32, 8), 0, stream>>>(x, ax, XtAll);

    // qkv_c[MS, 3072] = XtAll[0..MS) * Wqkv^T (+bias per col)
    gemm_proj<<<dim3(3 * D_MODEL / 128, MS / 128), 256, 0, stream>>>(
        XtAll, Wqkv, qkv_c, BiasQKV, MS, 3 * D_MODEL, C_IN);

    // fused aux-KV projection + attention; ATT lands in q-columns of qkv_c
    attn_fused<<<dim3(N_SP * N_HEAD * 4), 256, 0, stream>>>(
        XtAll, Wqkv, BiasQKV, qkv_c);

    // out[256, MS] = WoB * ATT^T + bo
    gemm_out<<<dim3(MS / 128, C_IN / 128), 256, 0, stream>>>(
        WoB, qkv_c, (float*)d_out, bo);
}